// Round 1
// baseline (149.989 us; speedup 1.0000x reference)
//
#include <hip/hip_runtime.h>

// Problem constants (from reference setup_inputs)
constexpr int BS  = 4;
constexpr int NJ  = 22;
constexpr int PTS = 64 * 64 * 64;          // h*w*d = 262144
constexpr int TPB = 256;
constexpr int VEC = 4;                      // points per thread
constexpr int BLOCKS_PER_B = PTS / (TPB * VEC);   // 256
constexpr int NBLOCKS = BS * BLOCKS_PER_B;        // 1024
constexpr float INV_2SIG2 = 1.0f / (2.0f * 5.0f * 5.0f);  // 1/50
constexpr long long NELEM = (long long)BS * NJ * PTS;      // 23,068,672

__global__ __launch_bounds__(TPB) void gauss_loss_main(
    const float* __restrict__ kpts_pred,   // [BS, 3, NJ]
    const float* __restrict__ heatmaps,    // [BS, NJ, PTS]
    const float* __restrict__ grids,       // [BS, PTS, 3]
    float* __restrict__ block_sums)        // [NBLOCKS]
{
    __shared__ float4 cj[NJ];              // (x, y, z, |c|^2) per joint
    const int b   = blockIdx.x / BLOCKS_PER_B;
    const int blk = blockIdx.x % BLOCKS_PER_B;
    const int tid = threadIdx.x;

    if (tid < NJ) {
        const float x = kpts_pred[b * 3 * NJ + 0 * NJ + tid];
        const float y = kpts_pred[b * 3 * NJ + 1 * NJ + tid];
        const float z = kpts_pred[b * 3 * NJ + 2 * NJ + tid];
        cj[tid] = make_float4(x, y, z, x * x + y * y + z * z);
    }
    __syncthreads();

    // 4 consecutive points per thread; p0 multiple of 4 -> all float4 loads aligned
    const int p0 = (blk * TPB + tid) * VEC;

    // grids[b, p0..p0+3, 0..2] : 12 floats = 3 aligned float4
    const float4* gptr = reinterpret_cast<const float4*>(
        grids + (size_t)b * PTS * 3 + (size_t)p0 * 3);
    const float4 ga = gptr[0];
    const float4 gb = gptr[1];
    const float4 gc = gptr[2];

    const float gx[VEC] = {ga.x, ga.w, gb.z, gc.y};
    const float gy[VEC] = {ga.y, gb.x, gb.w, gc.z};
    const float gz[VEC] = {ga.z, gb.y, gc.x, gc.w};
    float g2[VEC];
    #pragma unroll
    for (int i = 0; i < VEC; ++i)
        g2[i] = gx[i] * gx[i] + gy[i] * gy[i] + gz[i] * gz[i];

    const float* hbase = heatmaps + (size_t)b * NJ * PTS + p0;

    float acc = 0.0f;
    #pragma unroll
    for (int j = 0; j < NJ; ++j) {
        const float4 hv = *reinterpret_cast<const float4*>(hbase + (size_t)j * PTS);
        const float h[VEC] = {hv.x, hv.y, hv.z, hv.w};
        const float4 c = cj[j];   // wave-uniform LDS broadcast (conflict-free)
        #pragma unroll
        for (int i = 0; i < VEC; ++i) {
            // d2 = |g|^2 - 2 g.c + |c|^2
            const float dot = gx[i] * c.x + gy[i] * c.y + gz[i] * c.z;
            const float d2  = (g2[i] - 2.0f * dot) + c.w;
            // faithful to reference: exp(-d2) THEN scale by 1/(2 sigma^2)
            const float gauss = __expf(-d2) * INV_2SIG2;
            const float sg    = __fdividef(1.0f, 1.0f + __expf(-h[i]));
            const float diff  = gauss - sg;
            acc = fmaf(diff, diff, acc);
        }
    }

    // Block reduction: intra-wave shuffle (wave64) then LDS across 4 waves
    #pragma unroll
    for (int off = 32; off > 0; off >>= 1)
        acc += __shfl_down(acc, off, 64);

    __shared__ float wsum[TPB / 64];
    if ((tid & 63) == 0) wsum[tid >> 6] = acc;
    __syncthreads();
    if (tid == 0)
        block_sums[blockIdx.x] = wsum[0] + wsum[1] + wsum[2] + wsum[3];
}

__global__ __launch_bounds__(TPB) void gauss_loss_final(
    const float* __restrict__ block_sums,
    float* __restrict__ out)
{
    const int tid = threadIdx.x;
    float acc = 0.0f;
    for (int i = tid; i < NBLOCKS; i += TPB)
        acc += block_sums[i];

    #pragma unroll
    for (int off = 32; off > 0; off >>= 1)
        acc += __shfl_down(acc, off, 64);

    __shared__ float wsum[TPB / 64];
    if ((tid & 63) == 0) wsum[tid >> 6] = acc;
    __syncthreads();
    if (tid == 0) {
        const float total = wsum[0] + wsum[1] + wsum[2] + wsum[3];
        out[0] = 0.5f * total / (float)NELEM;
    }
}

extern "C" void kernel_launch(void* const* d_in, const int* in_sizes, int n_in,
                              void* d_out, int out_size, void* d_ws, size_t ws_size,
                              hipStream_t stream) {
    // Inputs in setup_inputs() order:
    //   d_in[0] = kpts_gt   [4,3,22]   (UNUSED by the reference loss)
    //   d_in[1] = kpts_pred [4,3,22]
    //   d_in[2] = heatmaps  [4,22,64,64,64]
    //   d_in[3] = grids     [4, 64*64*64, 3]
    const float* kpts_pred = (const float*)d_in[1];
    const float* heatmaps  = (const float*)d_in[2];
    const float* grids     = (const float*)d_in[3];
    float* out = (float*)d_out;
    float* bsums = (float*)d_ws;   // NBLOCKS floats of scratch

    gauss_loss_main<<<NBLOCKS, TPB, 0, stream>>>(kpts_pred, heatmaps, grids, bsums);
    gauss_loss_final<<<1, TPB, 0, stream>>>(bsums, out);
}